// Round 3
// baseline (508.868 us; speedup 1.0000x reference)
//
#include <hip/hip_runtime.h>

// CKConv: y[b,o,n] = sum_i (x[b,i] * k[o,i])_causal[n] + bias[o]
// k is rank-33 over (oi) x t:  k[oi,t] = sum_r hbT[r][L-1-t... ] (see prep)
// FFT path: Yf[b,o,f] = sum_i Xf[b,i,f] * Kf[o,i,f],  Kf[oi,f] = sum_r Hf[r,f]*M2[r,i,o]

#define LSEQ   8192
#define N2     8192      // half-size complex FFT length
#define HDIM   32
#define NB     33        // 32 SIREN basis rows + constant row (for b3)
#define NROWS  512       // B*Ci = 8*64
#define NFREQ  8193      // rfft bins of N=16384
#define FSTRIDE 8200     // complex row stride (64B-aligned rows: 8200*8 = 65600)
#define FBLK   4
#define OMEGA0 30.0f
#define TWOPI  6.283185307179586f

// ---------------------------------------------------------------- prep: SIREN basis
__global__ __launch_bounds__(256) void prep_basis_kernel(
    const float* __restrict__ w1, const float* __restrict__ b1,
    const float* __restrict__ w2, const float* __restrict__ b2,
    float* __restrict__ hbT)   // [NB][LSEQ]; hbT[r][s] = h[L-1-s, r], hbT[32][s] = 1
{
    int t = blockIdx.x * 256 + threadIdx.x;      // grid = 32 blocks
    float rel = -1.0f + 2.0f * (float)t / (float)(LSEQ - 1);
    float h1[HDIM];
    #pragma unroll
    for (int j = 0; j < HDIM; ++j)
        h1[j] = sinf(OMEGA0 * fmaf(rel, w1[j], b1[j]));
    for (int j = 0; j < HDIM; ++j) {
        float acc = b2[j];
        #pragma unroll 8
        for (int j2 = 0; j2 < HDIM; ++j2)
            acc = fmaf(h1[j2], w2[j2 * HDIM + j], acc);
        hbT[j * LSEQ + (LSEQ - 1 - t)] = sinf(OMEGA0 * acc);
    }
    hbT[HDIM * LSEQ + t] = 1.0f;
}

// ---------------------------------------------------------------- prep: M2[r][i][o] = w3[r, o*64+i] (r<32), b3[o*64+i] (r=32)
__global__ __launch_bounds__(256) void prep_m2_kernel(
    const float* __restrict__ w3, const float* __restrict__ b3,
    float* __restrict__ M2)
{
    int idx = blockIdx.x * 256 + threadIdx.x;    // grid = 528 blocks -> 135168 = 33*64*64
    if (idx >= NB * 64 * 64) return;
    int o = idx & 63;
    int i = (idx >> 6) & 63;
    int r = idx >> 12;
    M2[idx] = (r < HDIM) ? w3[r * 4096 + o * 64 + i] : b3[o * 64 + i];
}

// ---------------------------------------------------------------- shared 8192-pt C2C FFT core (radix-2 DIF, bit-reversal at end)
// twc/tws: 2048-entry quarter table, W_8192^t = twc[t] + i*tws[t] for t<2048;
// t in [2048,4096): W^t = W^{t-2048} * (-i)  ->  c' = s0, s' = -c0
__device__ __forceinline__ void fft8192_core(float* re, float* im,
                                             const float* twc, const float* tws, int tid)
{
    for (int shift = 12; shift >= 0; --shift) {
        int m = 1 << shift;
        __syncthreads();
        for (int u = tid; u < 4096; u += 256) {
            int j = u & (m - 1);
            int a = ((u >> shift) << (shift + 1)) + j;
            int b = a + m;
            float ar = re[a], ai = im[a];
            float br = re[b], bi = im[b];
            re[a] = ar + br; im[a] = ai + bi;
            float dr = ar - br, di = ai - bi;
            int tw = j << (12 - shift);          // in [0, 4096)
            int tt = tw & 2047;
            float c0 = twc[tt], s0 = tws[tt];
            bool hi = (tw & 2048) != 0;
            float c = hi ? s0 : c0;
            float s = hi ? -c0 : s0;
            re[b] = dr * c - di * s;
            im[b] = dr * s + di * c;
        }
    }
    __syncthreads();
    // bit reversal (13 bits)
    for (int idx = tid; idx < N2; idx += 256) {
        unsigned r = __brev((unsigned)idx) >> 19;
        if ((int)r > idx) {
            float tr = re[idx], ti = im[idx];
            re[idx] = re[r]; im[idx] = im[r];
            re[r]  = tr;     im[r]  = ti;
        }
    }
    __syncthreads();
}

__device__ __forceinline__ void build_twiddles(float* twc, float* tws, int tid)
{
    for (int t = tid; t < 2048; t += 256) {
        float s, c;
        sincosf(-TWOPI * (float)t / 8192.0f, &s, &c);
        twc[t] = c; tws[t] = s;
    }
}

// ---------------------------------------------------------------- forward rfft of zero-padded length-8192 real rows
// in: rows of 8192 reals; out: rows of NFREQ complex (stride FSTRIDE)
__global__ __launch_bounds__(256) void rfft_rows_kernel(
    const float* __restrict__ in, float* __restrict__ outF)
{
    __shared__ float re[N2], im[N2];
    __shared__ float twc[2048], tws[2048];
    int tid = threadIdx.x;
    int row = blockIdx.x;

    build_twiddles(twc, tws, tid);

    // pack: z[n] = g[2n] + i g[2n+1]; g has 8192 samples then zeros to 16384 -> z[n>=4096] = 0
    const float2* zin = (const float2*)(in + (long long)row * LSEQ);
    for (int n = tid; n < 4096; n += 256) {
        float2 v = zin[n];
        re[n] = v.x;          im[n] = v.y;
        re[n + 4096] = 0.0f;  im[n + 4096] = 0.0f;
    }
    fft8192_core(re, im, twc, tws, tid);

    // Hermitian fold: G[k] = Ze[k] + W_16384^k * Zo[k], k = 0..8192
    float2* out = (float2*)outF + (long long)row * FSTRIDE;
    for (int k = tid; k <= 8192; k += 256) {
        int k1 = k & (N2 - 1);
        int k2 = (N2 - k) & (N2 - 1);
        float zr = re[k1], zi = im[k1];
        float wr = re[k2], wi = im[k2];
        float er = 0.5f * (zr + wr), ei = 0.5f * (zi - wi);     // Ze
        float pr = 0.5f * (zi + wi), pi = 0.5f * (wr - zr);     // Zo
        float s, c;
        sincosf(-TWOPI * (float)k / 16384.0f, &s, &c);
        out[k] = make_float2(er + c * pr - s * pi,
                             ei + c * pi + s * pr);
    }
}

// ---------------------------------------------------------------- frequency-domain contraction (in-place on XYf)
// Per block: FBLK freqs. Build Ks[f][i][o] = Kf[o*64+i, f] = sum_r M2[r][i][o]*Hs[r][f] in LDS,
// then Y[b,o,f] = sum_i Xs[b*64+i][f] * Ks[f][i][o], written back over XYf columns.
__global__ __launch_bounds__(256) void contract_kernel(
    const float* __restrict__ Hf, const float* __restrict__ M2,
    float* XYf)
{
    __shared__ __align__(16) float2 Xs[NROWS][FBLK];   // 16 KB
    __shared__ __align__(16) float2 Hs[NB][FBLK];      // ~1 KB
    __shared__ float2 Ks[FBLK][64][64];                // 128 KB
    int tid = threadIdx.x;
    int f0 = blockIdx.x * FBLK;

    for (int idx = tid; idx < NB * FBLK; idx += 256) {
        int r = idx >> 2, f = idx & 3;
        int fk = f0 + f;
        float2 v = make_float2(0.f, 0.f);
        if (fk < NFREQ) v = ((const float2*)Hf)[(long long)r * FSTRIDE + fk];
        Hs[r][f] = v;
    }
    for (int idx = tid; idx < NROWS * FBLK; idx += 256) {
        int rowi = idx >> 2, f = idx & 3;
        int fk = f0 + f;
        float2 v = make_float2(0.f, 0.f);
        if (fk < NFREQ) v = ((const float2*)XYf)[(long long)rowi * FSTRIDE + fk];
        Xs[rowi][f] = v;
    }
    __syncthreads();

    int o = tid & 63, q = tid >> 6;                    // q in 0..3
    // ---- K build: this thread covers i = q*16 .. q*16+15, in chunks of 4 (reg pressure)
    for (int iic = 0; iic < 4; ++iic) {
        int ibase = (q << 4) + (iic << 2);
        float2 acc[4][FBLK];
        #pragma unroll
        for (int a = 0; a < 4; ++a)
            #pragma unroll
            for (int f = 0; f < FBLK; ++f) acc[a][f] = make_float2(0.f, 0.f);
        const float* mp = M2 + (ibase << 6) + o;       // M2[r][i][o]
        #pragma unroll 3
        for (int r = 0; r < NB; ++r) {
            const float4* hp = (const float4*)(&Hs[r][0]);
            float4 ha = hp[0], hb = hp[1];             // 4 complex twiddle-weights
            #pragma unroll
            for (int a = 0; a < 4; ++a) {
                float m = mp[(r << 12) + (a << 6)];
                acc[a][0].x = fmaf(m, ha.x, acc[a][0].x); acc[a][0].y = fmaf(m, ha.y, acc[a][0].y);
                acc[a][1].x = fmaf(m, ha.z, acc[a][1].x); acc[a][1].y = fmaf(m, ha.w, acc[a][1].y);
                acc[a][2].x = fmaf(m, hb.x, acc[a][2].x); acc[a][2].y = fmaf(m, hb.y, acc[a][2].y);
                acc[a][3].x = fmaf(m, hb.z, acc[a][3].x); acc[a][3].y = fmaf(m, hb.w, acc[a][3].y);
            }
        }
        #pragma unroll
        for (int a = 0; a < 4; ++a) {
            int i = ibase + a;
            #pragma unroll
            for (int f = 0; f < FBLK; ++f) Ks[f][i][o] = acc[a][f];
        }
    }
    __syncthreads();

    // ---- einsum: thread handles (o, b=q) and (o, b=q+4)
    for (int bh = 0; bh < 2; ++bh) {
        int b = q + (bh << 2);
        float2 acc[FBLK];
        #pragma unroll
        for (int f = 0; f < FBLK; ++f) acc[f] = make_float2(0.f, 0.f);
        for (int i = 0; i < 64; ++i) {
            const float4* xp = (const float4*)(&Xs[(b << 6) + i][0]);
            float4 xa = xp[0], xb = xp[1];
            float xr[FBLK] = { xa.x, xa.z, xb.x, xb.z };
            float xi[FBLK] = { xa.y, xa.w, xb.y, xb.w };
            #pragma unroll
            for (int f = 0; f < FBLK; ++f) {
                float2 kv = Ks[f][i][o];
                acc[f].x = fmaf(xr[f], kv.x, fmaf(-xi[f], kv.y, acc[f].x));
                acc[f].y = fmaf(xr[f], kv.y, fmaf( xi[f], kv.x, acc[f].y));
            }
        }
        long long rw = (long long)((b << 6) + o) * FSTRIDE;
        #pragma unroll
        for (int f = 0; f < FBLK; ++f) {
            int fk = f0 + f;
            if (fk < NFREQ) ((float2*)XYf)[rw + fk] = acc[f];
        }
    }
}

// ---------------------------------------------------------------- inverse rfft + bias, keep first 8192 samples
__global__ __launch_bounds__(256) void irfft_rows_kernel(
    const float* __restrict__ Yf, const float* __restrict__ bias,
    float* __restrict__ out)
{
    __shared__ float re[N2], im[N2];
    __shared__ float twc[2048], tws[2048];
    int tid = threadIdx.x;
    int row = blockIdx.x;            // b*64 + o
    int o = row & 63;

    build_twiddles(twc, tws, tid);

    // Z[k] = Ze[k] + i*Zo[k];  Ze = (G[k]+conj(G[N2-k]))/2, Zo = (G[k]-conj(G[N2-k]))/2 * e^{+2pi i k/16384}
    // store conj(Z) for ifft-via-forward-fft
    const float2* G = (const float2*)Yf + (long long)row * FSTRIDE;
    for (int k = tid; k < N2; k += 256) {
        float2 gk = G[k];
        float2 gm = G[8192 - k];
        float er = 0.5f * (gk.x + gm.x), ei = 0.5f * (gk.y - gm.y);
        float pr = 0.5f * (gk.x - gm.x), pi = 0.5f * (gk.y + gm.y);
        float s, c;
        sincosf(TWOPI * (float)k / 16384.0f, &s, &c);
        float or_ = pr * c - pi * s;
        float oi_ = pr * s + pi * c;
        re[k] = er - oi_;            // Re(Z)
        im[k] = -(ei + or_);         // -Im(Z)  (conjugate)
    }
    fft8192_core(re, im, twc, tws, tid);

    // z[n] = conj(F)/N2 ; g[2n] = Re z, g[2n+1] = Im z ; add bias
    float bo = bias[o];
    const float scale = 1.0f / 8192.0f;
    float2* op = (float2*)(out + (long long)row * LSEQ);
    for (int n = tid; n < 4096; n += 256) {
        op[n] = make_float2(fmaf(re[n], scale, bo), fmaf(-im[n], scale, bo));
    }
}

// ---------------------------------------------------------------- launch
extern "C" void kernel_launch(void* const* d_in, const int* in_sizes, int n_in,
                              void* d_out, int out_size, void* d_ws, size_t ws_size,
                              hipStream_t stream)
{
    const float* x    = (const float*)d_in[0];
    const float* w1   = (const float*)d_in[1];
    const float* b1   = (const float*)d_in[2];
    const float* w2   = (const float*)d_in[3];
    const float* b2   = (const float*)d_in[4];
    const float* w3   = (const float*)d_in[5];
    const float* b3   = (const float*)d_in[6];
    const float* bias = (const float*)d_in[7];
    float* out = (float*)d_out;

    // workspace layout (floats): total ~9.35M floats = ~37.4 MB
    float* ws  = (float*)d_ws;
    float* hbT = ws;                               // NB*LSEQ          = 270336
    float* Hf  = hbT + NB * LSEQ;                  // NB*FSTRIDE*2     = 541200
    float* M2  = Hf + NB * FSTRIDE * 2;            // NB*64*64         = 135168
    float* XYf = M2 + NB * 64 * 64;                // NROWS*FSTRIDE*2  = 8396800

    prep_basis_kernel<<<dim3(LSEQ / 256), dim3(256), 0, stream>>>(w1, b1, w2, b2, hbT);
    prep_m2_kernel<<<dim3((NB * 64 * 64 + 255) / 256), dim3(256), 0, stream>>>(w3, b3, M2);
    rfft_rows_kernel<<<dim3(NB), dim3(256), 0, stream>>>(hbT, Hf);
    rfft_rows_kernel<<<dim3(NROWS), dim3(256), 0, stream>>>(x, XYf);
    contract_kernel<<<dim3((NFREQ + FBLK - 1) / FBLK), dim3(256), 0, stream>>>(Hf, M2, XYf);
    irfft_rows_kernel<<<dim3(NROWS), dim3(256), 0, stream>>>(XYf, bias, out);
}